// Round 9
// baseline (863.628 us; speedup 1.0000x reference)
//
#include <hip/hip_runtime.h>
#include <cstdint>
#include <cstddef>

#define NN 200000
#define NE 600000
#define NG 8192
#define C0 32
#define C1 128
#define C2 256
#define MLPH 256
#define NCLS 10
#define NB (3 * NN)
#define SCAN_BPB 1024
#define SCAN_NBLK ((NB + SCAN_BPB - 1) / SCAN_BPB)
#define NREP 8  // stats atomic replication

typedef __attribute__((ext_vector_type(8))) short short8b;  // 8 bf16 = 4 VGPR
typedef __attribute__((ext_vector_type(4))) float f32x4;

__device__ __forceinline__ void atomAddF(float* p, float v) { unsafeAtomicAdd(p, v); }

__device__ __forceinline__ float b2f(unsigned short u) {
  union { unsigned u; float f; } v; v.u = ((unsigned)u) << 16; return v.f;
}
__device__ __forceinline__ unsigned short f2b(float f) {  // RNE
  union { float f; unsigned u; } v; v.f = f;
  return (unsigned short)((v.u + 0x7FFF + ((v.u >> 16) & 1)) >> 16);
}

// ---------------- small utility kernels ----------------
__global__ __launch_bounds__(256) void k_fill(float* __restrict__ p, int n, float v) {
  int i = blockIdx.x * 256 + threadIdx.x;
  if (i < n) p[i] = v;
}

__global__ __launch_bounds__(256) void k_counts(const int* __restrict__ batch, float* __restrict__ counts) {
  int n = blockIdx.x * 256 + threadIdx.x;
  if (n < NN) atomAddF(&counts[batch[n]], 1.f);
}

// ---------------- CSR build: histogram (= degree), scan, place ----------------
__global__ __launch_bounds__(256) void k_hist(const int* __restrict__ dst, const int* __restrict__ et,
                                              int* __restrict__ cnt) {
  int e = blockIdx.x * 256 + threadIdx.x;
  if (e < NE) atomicAdd(&cnt[et[e] * NN + dst[e]], 1);
}

__global__ __launch_bounds__(256) void k_dinvI(const int* __restrict__ cnt, float* __restrict__ dinv) {
  int i = blockIdx.x * 256 + threadIdx.x;
  if (i < NB) { int c = cnt[i]; dinv[i] = (c > 0) ? 1.f / sqrtf((float)c) : 0.f; }
}

__global__ __launch_bounds__(256) void k_scan1(const int* __restrict__ cnt, int* __restrict__ starts,
                                               int* __restrict__ bsum) {
  __shared__ int sh[256];
  const int b0 = blockIdx.x * SCAN_BPB + threadIdx.x * 4;
  int v[4]; int tot = 0;
#pragma unroll
  for (int j = 0; j < 4; j++) {
    int b = b0 + j;
    v[j] = tot;
    tot += (b < NB) ? cnt[b] : 0;
  }
  sh[threadIdx.x] = tot;
  __syncthreads();
  for (int ofs = 1; ofs < 256; ofs <<= 1) {
    int add = (threadIdx.x >= ofs) ? sh[threadIdx.x - ofs] : 0;
    __syncthreads();
    sh[threadIdx.x] += add;
    __syncthreads();
  }
  const int excl = (threadIdx.x == 0) ? 0 : sh[threadIdx.x - 1];
#pragma unroll
  for (int j = 0; j < 4; j++) {
    int b = b0 + j;
    if (b < NB) starts[b] = excl + v[j];
  }
  if (threadIdx.x == 255) bsum[blockIdx.x] = sh[255];
}

__global__ void k_scan2(int* __restrict__ bsum) {
  if (threadIdx.x == 0) {
    int acc = 0;
    for (int i = 0; i < SCAN_NBLK; i++) { int t = bsum[i]; bsum[i] = acc; acc += t; }
  }
}

__global__ __launch_bounds__(256) void k_scan3(int* __restrict__ starts, const int* __restrict__ bsum) {
  int b = blockIdx.x * 256 + threadIdx.x;
  if (b < NB) starts[b] += bsum[b / SCAN_BPB];
}

// After k_place, starts[b] == end(b); list for bin b = [b ? starts[b-1] : 0, starts[b])
__global__ __launch_bounds__(256) void k_place(const int* __restrict__ src, const int* __restrict__ dst,
                                               const int* __restrict__ et, int* __restrict__ starts,
                                               int* __restrict__ esrc) {
  int e = blockIdx.x * 256 + threadIdx.x;
  if (e >= NE) return;
  int b = et[e] * NN + dst[e];
  int pos = atomicAdd(&starts[b], 1);
  esrc[pos] = src[e];
}

// ---------------- weight prep: fragment-ordered bf16 ----------------
// [m:4][p:COUT/64][kk:CIN/32][ct:4][l:64][j:8]; ki = kk*32+(l>>4)*4+(j&3)+16*(j>>2), c = p*64+ct*16+(l&15)
__global__ __launch_bounds__(256) void k_prepw(const float* __restrict__ Wid, const float* __restrict__ Wc,
                                               unsigned short* __restrict__ Wtf, int CIN_, int COUT_) {
  int i = blockIdx.x * 256 + threadIdx.x;
  if (i >= 4 * CIN_ * COUT_) return;
  int j = i & 7, lq = (i >> 3) & 63, ct = (i >> 9) & 3;
  int rest = i >> 11;
  int KK = CIN_ / 32, NP = COUT_ / 64;
  int kk = rest % KK; rest /= KK;
  int p = rest % NP; int m = rest / NP;
  int ki = kk * 32 + (lq >> 4) * 4 + (j & 3) + 16 * (j >> 2);
  int c = p * 64 + ct * 16 + (lq & 15);
  float wv = (m == 0) ? Wid[(size_t)ki * COUT_ + c] : Wc[(size_t)((m - 1) * CIN_ + ki) * COUT_ + c];
  Wtf[i] = f2b(wv);
}

// ---------------- gather-reduce aggregation (CSR) ----------------
// aggXb[t*nloc+nl][c] = bf16( dinv_dst * sum_{e in list(t, lo+nl)} dinv_src * h[src][c] )
template <int CIN, typename TIN>
__global__ __launch_bounds__(256) void k_agg(const int* __restrict__ starts, const int* __restrict__ esrc,
                                             const float* __restrict__ dinv, const TIN* __restrict__ h,
                                             unsigned short* __restrict__ aggXb, int lo, int nloc) {
  constexpr int TPB = (CIN == 32) ? 32 : 64;
  constexpr int V = CIN / TPB;  // 1 or 2
  const int idx = blockIdx.x * 256 + threadIdx.x;
  const int bl = idx / TPB;
  const int lane = idx % TPB;
  if (bl >= 3 * nloc) return;
  const int t = bl / nloc;
  const int bin = t * NN + lo + (bl - t * nloc);
  const int s = (bin == 0) ? 0 : starts[bin - 1];
  const int e2 = starts[bin];
  float acc[V];
#pragma unroll
  for (int j = 0; j < V; j++) acc[j] = 0.f;
  for (int i = s; i < e2; i++) {
    const int sn = esrc[i];
    const float dv = dinv[(size_t)t * NN + sn];
    if (dv == 0.f) continue;
    const TIN* hp = h + (size_t)sn * CIN + lane * V;
#pragma unroll
    for (int j = 0; j < V; j++) {
      float v;
      if constexpr (sizeof(TIN) == 2) v = b2f(((const unsigned short*)hp)[j]);
      else v = ((const float*)hp)[j];
      acc[j] = fmaf(v, dv, acc[j]);
    }
  }
  const float dvd = dinv[bin];
  unsigned short* op = aggXb + (size_t)bl * CIN + lane * V;
#pragma unroll
  for (int j = 0; j < V; j++) op[j] = f2b(acc[j] * dvd);
}

// ---------------- fused finish: persistent blocks, bf16 MFMA ----------------
// 512 threads = 8 waves; each wave owns 16 rows of a 128-row supertile.
// Block = (panel p, xcd, set): stages all-m panel weights to LDS ONCE, then loops
// over supertiles st = xcd + 8*(set + SETS*k) with A-fragments double-buffered in
// registers (A/B, static indexing). Epilogue is wave-private (own LDS strip) -> the
// only __syncthreads in the kernel is after the weight stage.
#define LOADF(A0, A1, stv)                                                                     \
  {                                                                                            \
    const int lnb_ = (stv) * 128 + w * 16 + lr;                                                \
    const bool v_ = lnb_ < nloc;                                                               \
    _Pragma("unroll") for (int m_ = 1; m_ < 4; m_++) {                                         \
      const unsigned short* ar_ = aggXb + ((size_t)(m_ - 1) * nloc + lnb_) * CIN;              \
      _Pragma("unroll") for (int kk_ = 0; kk_ < KK; kk_++) {                                   \
        A0[m_][kk_] = v_ ? *(const ushort4*)(ar_ + kk_ * 32 + lq * 4) : z4;                    \
        A1[m_][kk_] = v_ ? *(const ushort4*)(ar_ + kk_ * 32 + 16 + lq * 4) : z4;               \
      }                                                                                        \
    }                                                                                          \
    if constexpr (INBF16) {                                                                    \
      const unsigned short* xr_ = (const unsigned short*)Xv + (size_t)(lo + lnb_) * CIN;       \
      _Pragma("unroll") for (int kk_ = 0; kk_ < KK; kk_++) {                                   \
        A0[0][kk_] = v_ ? *(const ushort4*)(xr_ + kk_ * 32 + lq * 4) : z4;                     \
        A1[0][kk_] = v_ ? *(const ushort4*)(xr_ + kk_ * 32 + 16 + lq * 4) : z4;                \
      }                                                                                        \
    } else {                                                                                   \
      const float* xr_ = (const float*)Xv + (size_t)(lo + lnb_) * CIN;                         \
      _Pragma("unroll") for (int kk_ = 0; kk_ < KK; kk_++) {                                   \
        float4 v0_ = v_ ? *(const float4*)(xr_ + kk_ * 32 + lq * 4) : make_float4(0, 0, 0, 0); \
        float4 v1_ = v_ ? *(const float4*)(xr_ + kk_ * 32 + 16 + lq * 4) : make_float4(0, 0, 0, 0); \
        A0[0][kk_] = make_ushort4(f2b(v0_.x), f2b(v0_.y), f2b(v0_.z), f2b(v0_.w));             \
        A1[0][kk_] = make_ushort4(f2b(v1_.x), f2b(v1_.y), f2b(v1_.z), f2b(v1_.w));             \
      }                                                                                        \
    }                                                                                          \
  }

#define COMPUTE(A0, A1, stv)                                                                   \
  {                                                                                            \
    f32x4 run_[4];                                                                             \
    _Pragma("unroll") for (int ct_ = 0; ct_ < 4; ct_++) run_[ct_] = (f32x4){0.f, 0.f, 0.f, 0.f}; \
    _Pragma("unroll") for (int m_ = 0; m_ < 4; m_++) {                                         \
      f32x4 acc_[4];                                                                           \
      _Pragma("unroll") for (int ct_ = 0; ct_ < 4; ct_++) acc_[ct_] = (f32x4){0.f, 0.f, 0.f, 0.f}; \
      _Pragma("unroll") for (int kk_ = 0; kk_ < KK; kk_++) {                                   \
        union { ushort4 u4[2]; short8b v; } fa_;                                               \
        fa_.u4[0] = A0[m_][kk_]; fa_.u4[1] = A1[m_][kk_];                                      \
        _Pragma("unroll") for (int ct_ = 0; ct_ < 4; ct_++)                                    \
          acc_[ct_] = __builtin_amdgcn_mfma_f32_16x16x32_bf16(                                 \
              fa_.v, wlds[(m_ * KK + kk_) * 256 + ct_ * 64 + l], acc_[ct_], 0, 0, 0);          \
      }                                                                                        \
      _Pragma("unroll") for (int ct_ = 0; ct_ < 4; ct_++) {                                    \
        _Pragma("unroll") for (int j_ = 0; j_ < 4; j_++)                                       \
          run_[ct_][j_] += fmaxf(acc_[ct_][j_] + bb[m_][ct_], 0.f);                            \
      }                                                                                        \
    }                                                                                          \
    _Pragma("unroll") for (int ct_ = 0; ct_ < 4; ct_++) {                                      \
      _Pragma("unroll") for (int j_ = 0; j_ < 4; j_++)                                         \
        strip[(lq * 4 + j_) * 68 + ct_ * 16 + lr] = run_[ct_][j_];                             \
    }                                                                                          \
    const int lnw_ = (stv) * 128 + w * 16;                                                     \
    int rlim_ = nloc - lnw_;                                                                   \
    rlim_ = rlim_ < 0 ? 0 : (rlim_ > 16 ? 16 : rlim_);                                         \
    if constexpr (WRITEOUT) {                                                                  \
      const int r_ = l >> 2, cg_ = (l & 3) * 16;                                               \
      if (r_ < rlim_) {                                                                        \
        unsigned short* orow_ = outb + (size_t)(lo + lnw_ + r_) * COUT + c0 + cg_;             \
        _Pragma("unroll") for (int g4_ = 0; g4_ < 4; g4_++) {                                  \
          ushort4 o_;                                                                          \
          o_.x = f2b(strip[r_ * 68 + cg_ + g4_ * 4 + 0]);                                      \
          o_.y = f2b(strip[r_ * 68 + cg_ + g4_ * 4 + 1]);                                      \
          o_.z = f2b(strip[r_ * 68 + cg_ + g4_ * 4 + 2]);                                      \
          o_.w = f2b(strip[r_ * 68 + cg_ + g4_ * 4 + 3]);                                      \
          *(ushort4*)(orow_ + g4_ * 4) = o_;                                                   \
        }                                                                                      \
      }                                                                                        \
    }                                                                                          \
    {                                                                                          \
      float s_ = 0.f, ss_ = 0.f, gs_ = 0.f;                                                    \
      int curg_ = -1;                                                                          \
      for (int r_ = 0; r_ < 16; r_++) {                                                        \
        if (r_ < rlim_) {                                                                      \
          float v_ = strip[r_ * 68 + l];                                                       \
          s_ += v_; ss_ += v_ * v_;                                                            \
          if constexpr (DOPOOL) {                                                              \
            int g_ = batch[lo + lnw_ + r_];                                                    \
            if (g_ != curg_) {                                                                 \
              if (curg_ >= 0) atomAddF(&pooled[(size_t)curg_ * C2 + c0 + l], gs_);             \
              gs_ = 0.f; curg_ = g_;                                                           \
            }                                                                                  \
            gs_ += v_;                                                                         \
          }                                                                                    \
        }                                                                                      \
      }                                                                                        \
      if constexpr (DOPOOL) {                                                                  \
        if (curg_ >= 0) atomAddF(&pooled[(size_t)curg_ * C2 + c0 + l], gs_);                   \
      }                                                                                        \
      if (rlim_ > 0) {                                                                         \
        atomAddF(&srep[c0 + l], s_);                                                           \
        atomAddF(&srep[COUT + c0 + l], ss_);                                                   \
      }                                                                                        \
    }                                                                                          \
  }

template <int CIN, int COUT, int SETS, bool INBF16, bool WRITEOUT, bool DOPOOL>
__global__ __launch_bounds__(512, 2) void k_fin(
    const void* __restrict__ Xv, const unsigned short* __restrict__ aggXb,
    int lo, int nloc, const unsigned short* __restrict__ Wtf,
    const float* __restrict__ bid, const float* __restrict__ bc,
    unsigned short* __restrict__ outb, float* __restrict__ stats,
    float* __restrict__ pooled, const int* __restrict__ batch) {
  constexpr int NP = COUT / 64;
  constexpr int KK = CIN / 32;
  constexpr int NFR = 4 * KK * 256;
  __shared__ __align__(16) short8b wlds[NFR];
  __shared__ float sstrip[8][16 * 68];

  const int b = blockIdx.x;
  const int xcd = b & 7, q = b >> 3;
  const int p = q % NP, set = q / NP;
  const int c0 = p * 64;
  const int tid = threadIdx.x, w = tid >> 6, l = tid & 63, lr = l & 15, lq = l >> 4;

  // ---- stage all-m weights for panel p (once per block) ----
  for (int f = tid; f < NFR; f += 512) {
    int m = f / (KK * 256), r = f - m * (KK * 256);
    wlds[f] = ((const short8b*)Wtf)[(size_t)(m * NP + p) * (KK * 256) + r];
  }
  // ---- hoist biases ----
  float bb[4][4];
#pragma unroll
  for (int m = 0; m < 4; m++) {
    const float* bp = (m == 0) ? bid : bc + (size_t)(m - 1) * COUT;
#pragma unroll
    for (int ct = 0; ct < 4; ct++) bb[m][ct] = bp[c0 + ct * 16 + lr];
  }
  __syncthreads();

  const int NT = (nloc + 127) >> 7;
  const int STEP = 8 * SETS;
  float* strip = &sstrip[w][0];
  float* srep = stats + (size_t)(q & (NREP - 1)) * 2 * COUT;
  const ushort4 z4 = make_ushort4(0, 0, 0, 0);

  ushort4 a0A[4][KK], a1A[4][KK], a0B[4][KK], a1B[4][KK];
  int st = xcd + 8 * set;
  if (st < NT) LOADF(a0A, a1A, st);
  while (st < NT) {
    const int stB = st + STEP;
    if (stB < NT) LOADF(a0B, a1B, stB);
    COMPUTE(a0A, a1A, st);
    st = stB;
    if (st >= NT) break;
    const int stA = st + STEP;
    if (stA < NT) LOADF(a0A, a1A, stA);
    COMPUTE(a0B, a1B, st);
    st += STEP;
  }
}

// ---------------- BN finalize (sums NREP replicas) -> per-channel scale/shift ----------------
__global__ __launch_bounds__(256) void k_bnfin(const float* __restrict__ stats, const float* __restrict__ gamma,
                                               const float* __restrict__ beta, float* __restrict__ sc,
                                               float* __restrict__ sh, int COUT) {
  int c = threadIdx.x;
  if (c < COUT) {
    float su = 0.f, ssu = 0.f;
    for (int r = 0; r < NREP; r++) {
      su += stats[(size_t)r * 2 * COUT + c];
      ssu += stats[(size_t)r * 2 * COUT + COUT + c];
    }
    const float invN = 1.f / (float)NN;
    float m = su * invN;
    float v = ssu * invN - m * m;
    float s = gamma[c] / sqrtf(v + 1e-5f);
    sc[c] = s;
    sh[c] = fmaf(-m, s, beta[c]);
  }
}

// ---------------- fold BN1 into out1 (bf16, in place) ----------------
__global__ __launch_bounds__(256) void k_bnfold(unsigned short* __restrict__ o, const float* __restrict__ sc,
                                                const float* __restrict__ sh) {
  size_t i8 = ((size_t)blockIdx.x * 256 + threadIdx.x) * 8;
  if (i8 >= (size_t)NN * C1) return;
  const int c = (int)(i8 & (C1 - 1));
  ushort4 a = *(ushort4*)(o + i8);
  ushort4 b = *(ushort4*)(o + i8 + 4);
  a.x = f2b(fmaf(b2f(a.x), sc[c + 0], sh[c + 0]));
  a.y = f2b(fmaf(b2f(a.y), sc[c + 1], sh[c + 1]));
  a.z = f2b(fmaf(b2f(a.z), sc[c + 2], sh[c + 2]));
  a.w = f2b(fmaf(b2f(a.w), sc[c + 3], sh[c + 3]));
  b.x = f2b(fmaf(b2f(b.x), sc[c + 4], sh[c + 4]));
  b.y = f2b(fmaf(b2f(b.y), sc[c + 5], sh[c + 5]));
  b.z = f2b(fmaf(b2f(b.z), sc[c + 6], sh[c + 6]));
  b.w = f2b(fmaf(b2f(b.w), sc[c + 7], sh[c + 7]));
  *(ushort4*)(o + i8) = a;
  *(ushort4*)(o + i8 + 4) = b;
}

// ---------------- MLP head: BN2 affine folded into pooled sums ----------------
__global__ __launch_bounds__(256) void k_mlp(const float* __restrict__ pooled, const float* __restrict__ counts,
                                             const float* __restrict__ sc2, const float* __restrict__ sh2,
                                             const float* __restrict__ Wf1, const float* __restrict__ bf1,
                                             const float* __restrict__ Wf2, const float* __restrict__ bf2,
                                             float* __restrict__ out) {
  __shared__ float feat[257];
  __shared__ float hid[256];
  const int g = blockIdx.x, t = threadIdx.x;
  const float cnt = counts[g];
  feat[t] = fmaf(sc2[t], pooled[(size_t)g * C2 + t], sh2[t] * cnt);
  if (t == 0) feat[256] = cnt * 0.025f;
  __syncthreads();
  float acc = bf1[t];
  for (int i = 0; i < 257; i++) acc = fmaf(feat[i], Wf1[(size_t)i * MLPH + t], acc);
  hid[t] = fmaxf(acc, 0.f);
  __syncthreads();
  if (t < NCLS) {
    float o = bf2[t];
    for (int j = 0; j < MLPH; j++) o = fmaf(hid[j], Wf2[(size_t)j * NCLS + t], o);
    out[(size_t)g * NCLS + t] = o;
  }
}

extern "C" void kernel_launch(void* const* d_in, const int* in_sizes, int n_in,
                              void* d_out, int out_size, void* d_ws, size_t ws_size,
                              hipStream_t stream) {
  const float* x = (const float*)d_in[0];
  const int* ei = (const int*)d_in[1];
  const int* et = (const int*)d_in[2];
  const int* batch = (const int*)d_in[3];
  const float* Wc0 = (const float*)d_in[4];
  const float* bc0 = (const float*)d_in[5];
  const float* Wid0 = (const float*)d_in[6];
  const float* bid0 = (const float*)d_in[7];
  const float* gm0 = (const float*)d_in[8];
  const float* bt0 = (const float*)d_in[9];
  const float* Wc1 = (const float*)d_in[10];
  const float* bc1 = (const float*)d_in[11];
  const float* Wid1 = (const float*)d_in[12];
  const float* bid1 = (const float*)d_in[13];
  const float* gm1 = (const float*)d_in[14];
  const float* bt1 = (const float*)d_in[15];
  const float* Wf1 = (const float*)d_in[16];
  const float* bf1 = (const float*)d_in[17];
  const float* Wf2 = (const float*)d_in[18];
  const float* bf2 = (const float*)d_in[19];
  const int* srcI = ei;
  const int* dstI = ei + NE;
  float* outp = (float*)d_out;

  char* ws = (char*)d_ws;
  size_t off = 0;
  auto take = [&](size_t bytes) -> char* {
    char* p = ws + off;
    off = (off + bytes + 255) & ~(size_t)255;
    return p;
  };
  float* dinv = (float*)take((size_t)NB * 4);
  int* cnt = (int*)take((size_t)NB * 4);
  int* starts = (int*)take((size_t)NB * 4);
  int* bsum = (int*)take((size_t)SCAN_NBLK * 4);
  int* esrc = (int*)take((size_t)NE * 4);
  float* stats1 = (float*)take((size_t)NREP * 2 * C1 * 4);
  float* stats2 = (float*)take((size_t)NREP * 2 * C2 * 4);
  float* sc1 = (float*)take(C1 * 4);
  float* sh1 = (float*)take(C1 * 4);
  float* sc2 = (float*)take(C2 * 4);
  float* sh2 = (float*)take(C2 * 4);
  float* counts = (float*)take((size_t)NG * 4);
  float* pooled = (float*)take((size_t)NG * C2 * 4);
  unsigned short* Wtf1 = (unsigned short*)take((size_t)4 * C0 * C1 * 2);
  unsigned short* Wtf2 = (unsigned short*)take((size_t)4 * C1 * C2 * 2);
  unsigned short* out1 = (unsigned short*)take((size_t)NN * C1 * 2);
  const size_t min_agg = (size_t)3 * 64 * C1 * 2;
  if (off + min_agg > ws_size) {
    k_fill<<<(out_size + 255) / 256, 256, 0, stream>>>(outp, out_size, 100.f);
    return;
  }
  unsigned short* aggXb = (unsigned short*)(ws + off);
  const size_t left = ws_size - off;
  long long ch1 = (long long)(left / ((size_t)3 * C0 * 2)) & ~127LL;
  long long ch2 = (long long)(left / ((size_t)3 * C1 * 2)) & ~127LL;
  if (ch1 > NN) ch1 = NN;
  if (ch2 > NN) ch2 = NN;

  dim3 blk(256);
  hipMemsetAsync(cnt, 0, (size_t)NB * 4, stream);
  hipMemsetAsync(stats1, 0, (size_t)NREP * 2 * C1 * 4, stream);
  hipMemsetAsync(stats2, 0, (size_t)NREP * 2 * C2 * 4, stream);
  hipMemsetAsync(counts, 0, (size_t)NG * 4, stream);
  hipMemsetAsync(pooled, 0, (size_t)NG * C2 * 4, stream);

  // ---- CSR build (histogram doubles as degree) ----
  k_hist<<<(NE + 255) / 256, blk, 0, stream>>>(dstI, et, cnt);
  k_dinvI<<<(NB + 255) / 256, blk, 0, stream>>>(cnt, dinv);
  k_counts<<<(NN + 255) / 256, blk, 0, stream>>>(batch, counts);
  k_scan1<<<SCAN_NBLK, blk, 0, stream>>>(cnt, starts, bsum);
  k_scan2<<<1, 64, 0, stream>>>(bsum);
  k_scan3<<<(NB + 255) / 256, blk, 0, stream>>>(starts, bsum);
  k_place<<<(NE + 255) / 256, blk, 0, stream>>>(srcI, dstI, et, starts, esrc);

  k_prepw<<<(4 * C0 * C1 + 255) / 256, blk, 0, stream>>>(Wid0, Wc0, Wtf1, C0, C1);
  k_prepw<<<(4 * C1 * C2 + 255) / 256, blk, 0, stream>>>(Wid1, Wc1, Wtf2, C1, C2);

  // ---- layer 1: x (f32, 32ch) -> out1 bf16 pre-BN (128ch) + stats1 ----
  for (long long lo = 0; lo < NN; lo += ch1) {
    const int nloc = (int)((NN - lo < ch1) ? (NN - lo) : ch1);
    k_agg<C0, float><<<(3 * nloc * 32 + 255) / 256, blk, 0, stream>>>(starts, esrc, dinv, x, aggXb,
                                                                      (int)lo, nloc);
    // grid = 8 xcd * NP(2) * SETS(48) = 768 blocks, 512 thr
    k_fin<C0, C1, 48, false, true, false><<<768, 512, 0, stream>>>(
        x, aggXb, (int)lo, nloc, Wtf1, bid0, bc0, out1, stats1, nullptr, nullptr);
  }
  k_bnfin<<<1, blk, 0, stream>>>(stats1, gm0, bt0, sc1, sh1, C1);
  k_bnfold<<<(int)(((size_t)NN * C1 / 8 + 255) / 256), blk, 0, stream>>>(out1, sc1, sh1);

  // ---- layer 2: out1 bf16 (BN1 folded) -> stats2 + pre-BN pooled ----
  for (long long lo = 0; lo < NN; lo += ch2) {
    const int nloc = (int)((NN - lo < ch2) ? (NN - lo) : ch2);
    k_agg<C1, unsigned short><<<(3 * nloc * 64 + 255) / 256, blk, 0, stream>>>(starts, esrc, dinv, out1,
                                                                               aggXb, (int)lo, nloc);
    // grid = 8 xcd * NP(4) * SETS(8) = 256 blocks, 512 thr
    k_fin<C1, C2, 8, true, false, true><<<256, 512, 0, stream>>>(
        out1, aggXb, (int)lo, nloc, Wtf2, bid1, bc1, nullptr, stats2, pooled, batch);
  }
  k_bnfin<<<1, blk, 0, stream>>>(stats2, gm1, bt1, sc2, sh2, C2);

  // ---- MLP head ----
  k_mlp<<<NG, blk, 0, stream>>>(pooled, counts, sc2, sh2, Wf1, bf1, Wf2, bf2, outp);
}